// Round 10
// baseline (144.193 us; speedup 1.0000x reference)
//
#include <hip/hip_runtime.h>
#include <hip/hip_bf16.h>

#define BB   16
#define CIN  256
#define COUT 256
#define WD   256
#define HH   64
#define WWS  64
#define NSP  4096      // HH*WWS
#define KW   9

typedef __attribute__((ext_vector_type(8))) short short8;
typedef __attribute__((ext_vector_type(4))) float f32x4;
typedef unsigned short ushort_t;
typedef unsigned int uint_t;

// workspace layout
#define S_BYTES (BB*CIN*4)                       // 16 KB
#define WT_OFF (S_BYTES)
#define WT_BYTES (BB*9*COUT*CIN*2)               // 18.87 MB
#define X_OFF (WT_OFF + WT_BYTES)
#define X_BYTES (BB*NSP*CIN*2)                   // 33.55 MB
#define ZP_OFF (X_OFF + X_BYTES)
#define ZP_BYTES 4096
#define WS_NEEDED ((size_t)(ZP_OFF + ZP_BYTES))

#define WAITVM0 asm volatile("s_waitcnt vmcnt(0)" ::: "memory")
#define WAITVM4 asm volatile("s_waitcnt vmcnt(4)" ::: "memory")

__device__ inline ushort_t f2bf(float f) {
    __hip_bfloat16 h = __float2bfloat16(f);
    return __builtin_bit_cast(ushort_t, h);
}

__device__ inline void gload_lds16(const ushort_t* g, ushort_t* l) {
    __builtin_amdgcn_global_load_lds(
        (const __attribute__((address_space(1))) void*)g,
        (__attribute__((address_space(3))) void*)l, 16, 0, 0);
}

// ---------------------------------------------------------------------------
// Kernel 1: style modulation
// ---------------------------------------------------------------------------
__global__ __launch_bounds__(256)
void style_kernel(const float* __restrict__ w,
                  const float* __restrict__ style_w,
                  const float* __restrict__ style_b,
                  float* __restrict__ s) {
    const int b  = blockIdx.x;
    const int ci = threadIdx.x;
    __shared__ float wsh[WD];
    wsh[ci] = w[b * WD + ci];
    __syncthreads();
    const float* row = style_w + ci * WD;
    float acc = style_b[ci];
    #pragma unroll 4
    for (int k = 0; k < WD; ++k) acc += wsh[k] * row[k];
    s[b * CIN + ci] = acc;
}

// ---------------------------------------------------------------------------
// Kernel 2: demodulated weights -> bf16, layout [b][tap][co][ci]
//           (block (0,0) also zero-fills the zp page used by conv)
// ---------------------------------------------------------------------------
__global__ __launch_bounds__(256)
void wt_kernel(const float* __restrict__ cw, const float* __restrict__ s,
               const float* __restrict__ scale_p, ushort_t* __restrict__ wt,
               float* __restrict__ zp) {
    const int co = blockIdx.x, b = blockIdx.y, ci = threadIdx.x;
    if (co == 0 && b == 0)
        ((float4*)zp)[ci] = make_float4(0.f, 0.f, 0.f, 0.f);
    const float sv = s[b * CIN + ci] * scale_p[0];
    const float* cp = cw + ((size_t)co * CIN + ci) * KW;
    float v[9];
    float ss = 0.f;
    #pragma unroll
    for (int t = 0; t < 9; ++t) { v[t] = cp[t] * sv; ss += v[t] * v[t]; }
    #pragma unroll
    for (int off = 32; off > 0; off >>= 1) ss += __shfl_down(ss, off);
    __shared__ float red[4];
    if ((ci & 63) == 0) red[ci >> 6] = ss;
    __syncthreads();
    const float dm = rsqrtf(red[0] + red[1] + red[2] + red[3] + 1e-8f);
    #pragma unroll
    for (int t = 0; t < 9; ++t)
        wt[((size_t)(b * 9 + t) * COUT + co) * CIN + ci] = f2bf(v[t] * dm);
}

// ---------------------------------------------------------------------------
// Kernel 3: x NCHW fp32 -> NHWC bf16  (xo[b][sp][ci]); uint4 stores
// ---------------------------------------------------------------------------
__global__ __launch_bounds__(256)
void xpose_kernel(const float* __restrict__ x, ushort_t* __restrict__ xo) {
    const int spt = blockIdx.x;
    const int cit = blockIdx.y;
    const int b   = blockIdx.z;
    const int t   = threadIdx.x;
    __shared__ ushort_t tile[64 * 72];
    const int sp0 = spt * 64, ci0 = cit * 64;
    {
        const int spq = t & 15, cil = t >> 4;
        #pragma unroll
        for (int i = 0; i < 4; ++i) {
            const int ci = cil + i * 16;
            const float4 v = *(const float4*)(x + ((size_t)(b * CIN + ci0 + ci)) * NSP + sp0 + spq * 4);
            tile[(spq * 4 + 0) * 72 + ci] = f2bf(v.x);
            tile[(spq * 4 + 1) * 72 + ci] = f2bf(v.y);
            tile[(spq * 4 + 2) * 72 + ci] = f2bf(v.z);
            tile[(spq * 4 + 3) * 72 + ci] = f2bf(v.w);
        }
    }
    __syncthreads();
    {
        const int g8 = t & 7, sp = t >> 3;     // sp 0..31
        #pragma unroll
        for (int i = 0; i < 2; ++i) {
            const int spp = sp + i * 32;
            uint4 v = *(const uint4*)&tile[spp * 72 + g8 * 8];
            *(uint4*)(xo + ((size_t)(b * NSP + sp0 + spp)) * CIN + ci0 + g8 * 8) = v;
        }
    }
}

// ---------------------------------------------------------------------------
// Kernel 4: implicit-GEMM conv. x-resident per ci-quarter + A global->reg.
//   512 blocks (16 b x 2 cohalf x 16 ntile), 256 threads = 4 waves (2Mx2N).
//   Block tile 128co x 256sp; wave tile 64co x 128sp -> acc[4][8].
//   LDS = x only: [6 rows][66 cols][64 ci] = 50.7 KB -> 2 blocks/CU.
//     col stride 128B (bank-aligned); slot = ciquad ^ (col&7) XOR-involution
//     on BOTH gload_lds source and ds_read -> uniform banks (min 8-cyc b128).
//     Restaged once per ci-quarter (4x; barriers only there).
//   A: global->reg (4 x dwordx4/tap from L2-resident wt), double-set af[2],
//     issued 2 taps ahead after MFMA burst, per-wave vmcnt(4), sched_barrier
//     fenced. Steady state: 0 barriers, 0 LDS writes, 8 ds_read + 32 MFMA.
// ---------------------------------------------------------------------------
__global__ __launch_bounds__(256, 2)
void conv_mfma_kernel(const ushort_t* __restrict__ wt,   // [b][9][256][256]
                      const ushort_t* __restrict__ xo,   // [b][4096][256]
                      const ushort_t* __restrict__ zp,   // zero page
                      float* __restrict__ out) {
    const int wg     = blockIdx.x;             // 0..511
    const int b      = (wg & 7) | (((wg >> 3) & 1) << 3);  // batch per XCD
    const int cohalf = (wg >> 4) & 1;
    const int ntile  = wg >> 5;                // 0..15
    const int y0     = ntile * 4;

    const int tid  = threadIdx.x;
    const int lane = tid & 63;
    const int w    = tid >> 6;                 // wave 0..3
    const int wm   = w >> 1;                   // co 64-half
    const int wn   = w & 1;                    // spatial 128-half
    const int wn2  = wn * 2;
    const int l15  = lane & 15;
    const int lg   = lane >> 4;

    __shared__ __align__(16) ushort_t lds_x[6 * 66 * 64];    // 50688 B

    // ---- A direct-load base: wt[((b*9+tap)*256 + co)*256 + ci] ----
    const ushort_t* pa = wt + (size_t)b * (9 * COUT * CIN)
                       + (uint_t)(cohalf * 128 + wm * 64 + l15) * CIN
                       + (uint_t)(lg * 8);
    const ushort_t* xob = xo + (size_t)b * (NSP * CIN);

    f32x4 acc[4][8];
    #pragma unroll
    for (int mi = 0; mi < 4; ++mi)
        #pragma unroll
        for (int ni = 0; ni < 8; ++ni) acc[mi][ni] = (f32x4){0.f, 0.f, 0.f, 0.f};

    short8 af[2][4];

    // ---- zero halo cols (0 and 65), rows 0..5, once ----
    if (tid < 96) {
        const int cell = tid >> 3;             // 0..11
        const int r = cell >> 1, c = (cell & 1) * 65;
        *(uint4*)&lds_x[(r * 66 + c) * 64 + (tid & 7) * 8] =
            make_uint4(0, 0, 0, 0);
    }

    // ---- x staging: 12 calls/wave cover 48 regions (6 rows x 8 col-groups).
    //      Dest linear (uniform base + lane*16B); source pre-XOR-swizzled.
    #define STAGE_X(qt)                                                        \
    {   _Pragma("unroll")                                                      \
        for (int i_ = 0; i_ < 12; ++i_) {                                      \
            const int cell_ = i_ * 4 + w;      /* 0..47 */                     \
            const int r_  = cell_ >> 3;        /* 0..5 */                      \
            const int c0_ = 1 + (cell_ & 7) * 8;                               \
            const int y_  = y0 - 1 + r_;                                       \
            const int c_  = c0_ + (lane >> 3);                                 \
            const int qq_ = (lane & 7) ^ (c_ & 7);                             \
            const ushort_t* src_ = (y_ >= 0 && y_ < HH)                        \
                ? (xob + (uint_t)(y_ * WWS + c_ - 1) * CIN + (qt) * 64         \
                       + qq_ * 8)                                              \
                : (zp + lane * 8);                                             \
            gload_lds16(src_, lds_x + (r_ * 66 + c0_) * 64 + lane * 8);        \
        }                                                                      \
    }

    // ---- one tap: wait af -> bf reads -> 32 MFMA -> issue af(u+2) ----
    #define TAPB(ch2, t, BX, PAQ, PAQN)                                        \
    {                                                                          \
        constexpr int u_ = (ch2) * 9 + (t);                                    \
        constexpr int P_ = u_ & 1;                                             \
        WAITVM4;                                                               \
        __builtin_amdgcn_sched_barrier(0);                                     \
        constexpr int ky_ = (t) / 3, kx_ = (t) % 3;                            \
        short8 bf_[8];                                                         \
        _Pragma("unroll")                                                      \
        for (int ni_ = 0; ni_ < 8; ++ni_)                                      \
            bf_[ni_] = *(const short8*)(lds_x + BX[kx_]                        \
                        + (((ni_ >> 2) + ky_) * 66) * 64 + (ni_ & 3) * 1024);  \
        __builtin_amdgcn_s_setprio(1);                                         \
        _Pragma("unroll")                                                      \
        for (int mi_ = 0; mi_ < 4; ++mi_)                                      \
            _Pragma("unroll")                                                  \
            for (int ni_ = 0; ni_ < 8; ++ni_)                                  \
                acc[mi_][ni_] = __builtin_amdgcn_mfma_f32_16x16x32_bf16(       \
                    bf_[ni_], af[P_][mi_], acc[mi_][ni_], 0, 0, 0);            \
        __builtin_amdgcn_s_setprio(0);                                         \
        __builtin_amdgcn_sched_barrier(0);                                     \
        {   /* issue af(u+2) into set P (just consumed) */                     \
            const ushort_t* ap_;                                               \
            if constexpr (u_ + 2 < 18) {                                       \
                constexpr int tap2_ = (u_ + 2) % 9;                            \
                constexpr int cgo_  = (u_ + 2) / 9;                            \
                ap_ = (PAQ) + tap2_ * 65536 + cgo_ * 32;                       \
            } else {                                                           \
                constexpr int tap2_ = u_ - 16;                                 \
                ap_ = (PAQN) + tap2_ * 65536;                                  \
            }                                                                  \
            _Pragma("unroll")                                                  \
            for (int mi_ = 0; mi_ < 4; ++mi_)                                  \
                af[P_][mi_] = *(const short8*)(ap_ + mi_ * 4096);              \
        }                                                                      \
        __builtin_amdgcn_sched_barrier(0);                                     \
    }

    // ---- prologue: stage x quarter 0; prime af(0), af(1) ----
    STAGE_X(0);
    #pragma unroll
    for (int mi = 0; mi < 4; ++mi)
        af[0][mi] = *(const short8*)(pa + mi * 4096);             // tap0 cg0
    #pragma unroll
    for (int mi = 0; mi < 4; ++mi)
        af[1][mi] = *(const short8*)(pa + 65536 + mi * 4096);     // tap1 cg0
    WAITVM0;
    asm volatile("s_waitcnt lgkmcnt(0)" ::: "memory");   // halo writes done
    __builtin_amdgcn_sched_barrier(0);
    __builtin_amdgcn_s_barrier();                        // all waves' x visible

    #pragma unroll 1
    for (int qt = 0; qt < 4; ++qt) {
        if (qt) {
            asm volatile("s_waitcnt lgkmcnt(0)" ::: "memory");  // own reads done
            __builtin_amdgcn_sched_barrier(0);
            __builtin_amdgcn_s_barrier();            // all waves done with x
            STAGE_X(qt);
            WAITVM0;                                 // own stage (and af) landed
            __builtin_amdgcn_sched_barrier(0);
            __builtin_amdgcn_s_barrier();            // all waves' x visible
        }
        const ushort_t* paq  = pa + qt * 64;             // + cg base this qtr
        const ushort_t* paqn = pa + ((qt + 1) & 3) * 64; // next quarter base

        int bx0[3], bx1[3];
        #pragma unroll
        for (int kx = 0; kx < 3; ++kx) {
            const int colb = (wn2 * 66 + l15 + kx) * 64;
            const int k7   = (l15 + kx) & 7;
            bx0[kx] = colb + ((0 + lg) ^ k7) * 8;
            bx1[kx] = colb + ((4 + lg) ^ k7) * 8;
        }

        TAPB(0,0,bx0,paq,paqn) TAPB(0,1,bx0,paq,paqn) TAPB(0,2,bx0,paq,paqn)
        TAPB(0,3,bx0,paq,paqn) TAPB(0,4,bx0,paq,paqn) TAPB(0,5,bx0,paq,paqn)
        TAPB(0,6,bx0,paq,paqn) TAPB(0,7,bx0,paq,paqn) TAPB(0,8,bx0,paq,paqn)
        TAPB(1,0,bx1,paq,paqn) TAPB(1,1,bx1,paq,paqn) TAPB(1,2,bx1,paq,paqn)
        TAPB(1,3,bx1,paq,paqn) TAPB(1,4,bx1,paq,paqn) TAPB(1,5,bx1,paq,paqn)
        TAPB(1,6,bx1,paq,paqn) TAPB(1,7,bx1,paq,paqn) TAPB(1,8,bx1,paq,paqn)
    }
    #undef TAPB
    #undef STAGE_X

    // drain outstanding dummy af loads before epilogue
    asm volatile("s_waitcnt vmcnt(0) lgkmcnt(0)" ::: "memory");
    __builtin_amdgcn_sched_barrier(0);

    // ---- epilogue: D col = co = l15, rows = sp -> f32x4 stores ----
    #pragma unroll
    for (int mi = 0; mi < 4; ++mi) {
        const int co = cohalf * 128 + wm * 64 + mi * 16 + l15;
        float* ob = out + ((size_t)(b * COUT + co)) * NSP
                  + ntile * 256 + wn * 128 + lg * 4;
        #pragma unroll
        for (int ni = 0; ni < 8; ++ni)
            *(f32x4*)(ob + (ni >> 2) * 64 + (ni & 3) * 16) = acc[mi][ni];
    }
}

// ---------------------------------------------------------------------------
// Fallback fp32 direct conv if workspace is too small.
// ---------------------------------------------------------------------------
__global__ __launch_bounds__(256)
void modconv_kernel(const float* __restrict__ x,
                    const float* __restrict__ cw,
                    const float* __restrict__ s,
                    const float* __restrict__ scale_p,
                    float* __restrict__ out) {
    const int tile = blockIdx.x;
    const int co   = blockIdx.y;
    const int b    = blockIdx.z;
    const int tid  = threadIdx.x;
    const float scale = scale_p[0];

    __shared__ float s_wt[CIN * KW];
    __shared__ float s_x[18 * 66];
    __shared__ float red[4];

    const float* cwb = cw + (size_t)co * CIN * KW;
    const float* sb  = s + b * CIN;
    float sumsq = 0.f;
    for (int i = tid; i < CIN * KW; i += 256) {
        float v = cwb[i] * scale * sb[i / KW];
        s_wt[i] = v;
        sumsq += v * v;
    }
    #pragma unroll
    for (int off = 32; off > 0; off >>= 1) sumsq += __shfl_down(sumsq, off);
    if ((tid & 63) == 0) red[tid >> 6] = sumsq;
    __syncthreads();
    const float demod = rsqrtf(red[0] + red[1] + red[2] + red[3] + 1e-8f);
    for (int i = tid; i < CIN * KW; i += 256) s_wt[i] *= demod;

    const int tx = tid & 63;
    const int tr = tid >> 6;
    const int y0 = tile * 16;
    float acc[4] = {0.f, 0.f, 0.f, 0.f};

    for (int ci = 0; ci < CIN; ++ci) {
        __syncthreads();
        const float* xb = x + ((size_t)(b * CIN + ci)) * (HH * WWS);
        for (int idx = tid; idx < 18 * 66; idx += 256) {
            const int r = idx / 66, c = idx % 66;
            const int yg = y0 - 1 + r, xg = c - 1;
            float v = 0.f;
            if (yg >= 0 && yg < HH && xg >= 0 && xg < WWS) v = xb[yg * WWS + xg];
            s_x[idx] = v;
        }
        __syncthreads();
        const float* wr = s_wt + ci * KW;
        const float w0 = wr[0], w1 = wr[1], w2 = wr[2];
        const float w3 = wr[3], w4 = wr[4], w5 = wr[5];
        const float w6 = wr[6], w7 = wr[7], w8 = wr[8];
        const int rbase = tr * 4;
        float xv[6][3];
        #pragma unroll
        for (int j = 0; j < 6; ++j)
            #pragma unroll
            for (int k = 0; k < 3; ++k) xv[j][k] = s_x[(rbase + j) * 66 + tx + k];
        #pragma unroll
        for (int i = 0; i < 4; ++i)
            acc[i] += w0 * xv[i][0] + w1 * xv[i][1] + w2 * xv[i][2]
                    + w3 * xv[i+1][0] + w4 * xv[i+1][1] + w5 * xv[i+1][2]
                    + w6 * xv[i+2][0] + w7 * xv[i+2][1] + w8 * xv[i+2][2];
    }
    float* ob = out + (((size_t)(b * COUT + co)) * HH + y0) * WWS + tx;
    #pragma unroll
    for (int i = 0; i < 4; ++i) ob[(tr * 4 + i) * WWS] = acc[i];
}

// ---------------------------------------------------------------------------
extern "C" void kernel_launch(void* const* d_in, const int* in_sizes, int n_in,
                              void* d_out, int out_size, void* d_ws, size_t ws_size,
                              hipStream_t stream) {
    const float* x       = (const float*)d_in[0];
    const float* w       = (const float*)d_in[1];
    const float* cw      = (const float*)d_in[2];
    const float* style_w = (const float*)d_in[3];
    const float* style_b = (const float*)d_in[4];
    const float* scale_p = (const float*)d_in[5];
    float*       out     = (float*)d_out;

    float*    s    = (float*)d_ws;
    ushort_t* wswt = (ushort_t*)((char*)d_ws + WT_OFF);
    ushort_t* wsx  = (ushort_t*)((char*)d_ws + X_OFF);
    float*    zp   = (float*)((char*)d_ws + ZP_OFF);

    style_kernel<<<dim3(BB), 256, 0, stream>>>(w, style_w, style_b, s);

    if (ws_size >= WS_NEEDED) {
        wt_kernel<<<dim3(COUT, BB), 256, 0, stream>>>(cw, s, scale_p, wswt, zp);
        xpose_kernel<<<dim3(64, 4, BB), 256, 0, stream>>>(x, wsx);
        conv_mfma_kernel<<<dim3(512), 256, 0, stream>>>(wswt, wsx,
                                                        (const ushort_t*)zp, out);
    } else {
        modconv_kernel<<<dim3(4, COUT, BB), 256, 0, stream>>>(x, cw, s, scale_p, out);
    }
}

// Round 11
// 109.841 us; speedup vs baseline: 1.3127x; 1.3127x over previous
//
#include <hip/hip_runtime.h>
#include <hip/hip_bf16.h>

#define BB   16
#define CIN  256
#define COUT 256
#define WD   256
#define HH   64
#define WWS  64
#define NSP  4096      // HH*WWS
#define KW   9

typedef __attribute__((ext_vector_type(8))) short short8;
typedef __attribute__((ext_vector_type(4))) float f32x4;
typedef unsigned short ushort_t;
typedef unsigned int uint_t;

// workspace layout
#define S_BYTES (BB*CIN*4)                       // 16 KB
#define WT_OFF (S_BYTES)
#define WT_BYTES (BB*9*COUT*CIN*2)               // 18.87 MB
#define X_OFF (WT_OFF + WT_BYTES)
#define X_BYTES (BB*NSP*CIN*2)                   // 33.55 MB
#define ZP_OFF (X_OFF + X_BYTES)
#define ZP_BYTES 4096
#define WS_NEEDED ((size_t)(ZP_OFF + ZP_BYTES))

#define WAITVM0 asm volatile("s_waitcnt vmcnt(0)" ::: "memory")
#define WAITVM2 asm volatile("s_waitcnt vmcnt(2)" ::: "memory")

__device__ inline ushort_t f2bf(float f) {
    __hip_bfloat16 h = __float2bfloat16(f);
    return __builtin_bit_cast(ushort_t, h);
}

__device__ inline void gload_lds16(const ushort_t* g, ushort_t* l) {
    __builtin_amdgcn_global_load_lds(
        (const __attribute__((address_space(1))) void*)g,
        (__attribute__((address_space(3))) void*)l, 16, 0, 0);
}

// ---------------------------------------------------------------------------
// Kernel 1: style modulation
// ---------------------------------------------------------------------------
__global__ __launch_bounds__(256)
void style_kernel(const float* __restrict__ w,
                  const float* __restrict__ style_w,
                  const float* __restrict__ style_b,
                  float* __restrict__ s) {
    const int b  = blockIdx.x;
    const int ci = threadIdx.x;
    __shared__ float wsh[WD];
    wsh[ci] = w[b * WD + ci];
    __syncthreads();
    const float* row = style_w + ci * WD;
    float acc = style_b[ci];
    #pragma unroll 4
    for (int k = 0; k < WD; ++k) acc += wsh[k] * row[k];
    s[b * CIN + ci] = acc;
}

// ---------------------------------------------------------------------------
// Kernel 2: demodulated weights -> bf16, layout [b][tap][co][ci]
//           (block (0,0) also zero-fills the zp page used by conv)
// ---------------------------------------------------------------------------
__global__ __launch_bounds__(256)
void wt_kernel(const float* __restrict__ cw, const float* __restrict__ s,
               const float* __restrict__ scale_p, ushort_t* __restrict__ wt,
               float* __restrict__ zp) {
    const int co = blockIdx.x, b = blockIdx.y, ci = threadIdx.x;
    if (co == 0 && b == 0)
        ((float4*)zp)[ci] = make_float4(0.f, 0.f, 0.f, 0.f);
    const float sv = s[b * CIN + ci] * scale_p[0];
    const float* cp = cw + ((size_t)co * CIN + ci) * KW;
    float v[9];
    float ss = 0.f;
    #pragma unroll
    for (int t = 0; t < 9; ++t) { v[t] = cp[t] * sv; ss += v[t] * v[t]; }
    #pragma unroll
    for (int off = 32; off > 0; off >>= 1) ss += __shfl_down(ss, off);
    __shared__ float red[4];
    if ((ci & 63) == 0) red[ci >> 6] = ss;
    __syncthreads();
    const float dm = rsqrtf(red[0] + red[1] + red[2] + red[3] + 1e-8f);
    #pragma unroll
    for (int t = 0; t < 9; ++t)
        wt[((size_t)(b * 9 + t) * COUT + co) * CIN + ci] = f2bf(v[t] * dm);
}

// ---------------------------------------------------------------------------
// Kernel 3: x NCHW fp32 -> NHWC bf16  (xo[b][sp][ci]); uint4 stores
// ---------------------------------------------------------------------------
__global__ __launch_bounds__(256)
void xpose_kernel(const float* __restrict__ x, ushort_t* __restrict__ xo) {
    const int spt = blockIdx.x;
    const int cit = blockIdx.y;
    const int b   = blockIdx.z;
    const int t   = threadIdx.x;
    __shared__ ushort_t tile[64 * 72];
    const int sp0 = spt * 64, ci0 = cit * 64;
    {
        const int spq = t & 15, cil = t >> 4;
        #pragma unroll
        for (int i = 0; i < 4; ++i) {
            const int ci = cil + i * 16;
            const float4 v = *(const float4*)(x + ((size_t)(b * CIN + ci0 + ci)) * NSP + sp0 + spq * 4);
            tile[(spq * 4 + 0) * 72 + ci] = f2bf(v.x);
            tile[(spq * 4 + 1) * 72 + ci] = f2bf(v.y);
            tile[(spq * 4 + 2) * 72 + ci] = f2bf(v.z);
            tile[(spq * 4 + 3) * 72 + ci] = f2bf(v.w);
        }
    }
    __syncthreads();
    {
        const int g8 = t & 7, sp = t >> 3;     // sp 0..31
        #pragma unroll
        for (int i = 0; i < 2; ++i) {
            const int spp = sp + i * 32;
            uint4 v = *(const uint4*)&tile[spp * 72 + g8 * 8];
            *(uint4*)(xo + ((size_t)(b * NSP + sp0 + spp)) * CIN + ci0 + g8 * 8) = v;
        }
    }
}

// ---------------------------------------------------------------------------
// Kernel 4: implicit-GEMM conv. R4 A-pipeline + R10 conflict-free x.
//   512 blocks (16 b x 2 cohalf x 16 ntile), 256 threads = 4 waves (2Mx2N).
//   Block tile 128co x 256sp; wave tile 64co x 128sp -> acc[4][8].
//   A: [3][128co][32ci] triple-buffer in LDS via global_load_lds
//      (2 calls/thread/tap, issued 2 taps ahead, counted vmcnt(2), per-tap
//      s_barrier). row&3 XOR-quad involution both sides -> uniform banks.
//   x: resident per ci-quarter [6][66 cols][64 ci] (128B col pitch,
//      8-slot XOR involution both sides; measured 0 conflicts in R10),
//      restaged 4x per block at quarter boundaries.
//   LDS 75264 B -> 2 blocks/CU. LDS ~65K cyc/CU < MFMA 89K cyc/CU.
// ---------------------------------------------------------------------------
__global__ __launch_bounds__(256, 2)
void conv_mfma_kernel(const ushort_t* __restrict__ wt,   // [b][9][256][256]
                      const ushort_t* __restrict__ xo,   // [b][4096][256]
                      const ushort_t* __restrict__ zp,   // zero page
                      float* __restrict__ out) {
    const int wg     = blockIdx.x;             // 0..511
    const int b      = (wg & 7) | (((wg >> 3) & 1) << 3);  // batch per XCD
    const int cohalf = (wg >> 4) & 1;
    const int ntile  = wg >> 5;                // 0..15
    const int y0     = ntile * 4;

    const int tid  = threadIdx.x;
    const int lane = tid & 63;
    const int w    = tid >> 6;                 // wave 0..3
    const int wm   = w >> 1;                   // co 64-half
    const int wn   = w & 1;                    // spatial 128-half
    const int wn2  = wn * 2;
    const int l15  = lane & 15;
    const int lg   = lane >> 4;

    __shared__ __align__(16) ushort_t lds_x[6 * 66 * 64];    // 50688 B
    __shared__ __align__(16) ushort_t lds_a[3 * 128 * 32];   // 24576 B

    // ---- A DMA (per thread): call i covers co row i*64 + (tid>>2) ----
    const int srcqA = ((tid & 3) ^ ((tid >> 2) & 3)) * 8;    // involution
    const ushort_t* paDMA = wt + (size_t)b * (9 * COUT * CIN)
                          + (uint_t)(cohalf * 128 + (tid >> 2)) * CIN + srcqA;
    const ushort_t* xob = xo + (size_t)b * (NSP * CIN);

    // ---- af read base: row = wm*64 + mi*16 + l15, slot = lg ^ (row&3) ----
    const int sA8   = (lg ^ (l15 & 3)) * 8;
    const int abase = (wm * 64 + l15) * 32 + sA8;

    f32x4 acc[4][8];
    #pragma unroll
    for (int mi = 0; mi < 4; ++mi)
        #pragma unroll
        for (int ni = 0; ni < 8; ++ni) acc[mi][ni] = (f32x4){0.f, 0.f, 0.f, 0.f};

    // ---- zero halo cols (0 and 65), rows 0..5, once ----
    if (tid < 96) {
        const int cell = tid >> 3;             // 0..11
        const int r = cell >> 1, c = (cell & 1) * 65;
        *(uint4*)&lds_x[(r * 66 + c) * 64 + (tid & 7) * 8] =
            make_uint4(0, 0, 0, 0);
    }

    // ---- x staging (R10-verbatim): 12 calls/thread, 48 regions ----
    #define STAGE_X(qt)                                                        \
    {   _Pragma("unroll")                                                      \
        for (int i_ = 0; i_ < 12; ++i_) {                                      \
            const int cell_ = i_ * 4 + w;      /* 0..47 */                     \
            const int r_  = cell_ >> 3;        /* 0..5 */                      \
            const int c0_ = 1 + (cell_ & 7) * 8;                               \
            const int y_  = y0 - 1 + r_;                                       \
            const int c_  = c0_ + (lane >> 3);                                 \
            const int qq_ = (lane & 7) ^ (c_ & 7);                             \
            const ushort_t* src_ = (y_ >= 0 && y_ < HH)                        \
                ? (xob + (uint_t)(y_ * WWS + c_ - 1) * CIN + (qt) * 64         \
                       + qq_ * 8)                                              \
                : (zp + lane * 8);                                             \
            gload_lds16(src_, lds_x + (r_ * 66 + c0_) * 64 + lane * 8);        \
        }                                                                      \
    }

    // ---- one tap: wait+barrier -> issue A(lt+2) -> frag reads -> 32 MFMA --
    #define TAPB(ch2, t, BX, QB, QN)                                           \
    {                                                                          \
        WAITVM2;                        /* A(lt) landed; A(lt+1) in flight */  \
        __builtin_amdgcn_sched_barrier(0);                                     \
        __builtin_amdgcn_s_barrier();   /* A(lt) visible to all waves */       \
        {   /* issue A(lt+2) into buf (lt+2)%3 */                              \
            const int lt2_ = (ch2) * 9 + (t) + 2;                              \
            const int tp_  = (lt2_ < 18) ? (lt2_ % 9) : (lt2_ - 18);           \
            const int cg_  = (lt2_ < 18) ? ((QB) + lt2_ / 9) : (QN);           \
            const uint_t ao_ = (uint_t)tp_ * 65536u + (uint_t)cg_ * 32u;       \
            ushort_t* ad_ = lds_a + (lt2_ % 3) * 4096 + tid * 8;               \
            gload_lds16(paDMA + ao_, ad_);                                     \
            gload_lds16(paDMA + 16384 + ao_, ad_ + 2048);                      \
        }                                                                      \
        const int ky_ = (t) / 3, kx_ = (t) % 3;                                \
        const ushort_t* ab_ = lds_a + (((ch2) * 9 + (t)) % 3) * 4096 + abase;  \
        short8 af_[4];                                                         \
        _Pragma("unroll")                                                      \
        for (int mi_ = 0; mi_ < 4; ++mi_)                                      \
            af_[mi_] = *(const short8*)(ab_ + mi_ * 512);                      \
        short8 bf_[8];                                                         \
        _Pragma("unroll")                                                      \
        for (int ni_ = 0; ni_ < 8; ++ni_)                                      \
            bf_[ni_] = *(const short8*)(lds_x + BX[kx_]                        \
                        + (((ni_ >> 2) + ky_) * 66) * 64 + (ni_ & 3) * 1024);  \
        __builtin_amdgcn_s_setprio(1);                                         \
        _Pragma("unroll")                                                      \
        for (int mi_ = 0; mi_ < 4; ++mi_)                                      \
            _Pragma("unroll")                                                  \
            for (int ni_ = 0; ni_ < 8; ++ni_)                                  \
                acc[mi_][ni_] = __builtin_amdgcn_mfma_f32_16x16x32_bf16(       \
                    bf_[ni_], af_[mi_], acc[mi_][ni_], 0, 0, 0);               \
        __builtin_amdgcn_s_setprio(0);                                         \
        __builtin_amdgcn_sched_barrier(0);                                     \
    }

    // ---- prologue: x quarter 0 + A(0)->buf0 + A(1)->buf1 ----
    STAGE_X(0);
    gload_lds16(paDMA, lds_a + tid * 8);                       // tap0 cg0 lo
    gload_lds16(paDMA + 16384, lds_a + 2048 + tid * 8);        // tap0 cg0 hi
    gload_lds16(paDMA + 65536, lds_a + 4096 + tid * 8);        // tap1 cg0 lo
    gload_lds16(paDMA + 65536 + 16384, lds_a + 6144 + tid * 8);
    WAITVM0;
    asm volatile("s_waitcnt lgkmcnt(0)" ::: "memory");   // halo writes done
    __builtin_amdgcn_sched_barrier(0);
    __builtin_amdgcn_s_barrier();                        // x + A visible

    #pragma unroll 1
    for (int qt = 0; qt < 4; ++qt) {
        if (qt) {
            // quarter boundary: restage x (A(0),A(1) of this quarter already
            // issued at previous quarter's taps 16,17)
            asm volatile("s_waitcnt lgkmcnt(0)" ::: "memory"); // own reads done
            __builtin_amdgcn_sched_barrier(0);
            __builtin_amdgcn_s_barrier();            // all waves done with x
            STAGE_X(qt);
            WAITVM0;                                 // x + pending A landed
            __builtin_amdgcn_sched_barrier(0);
            __builtin_amdgcn_s_barrier();            // visible to all waves
        }
        const int qb = qt * 2;                       // this quarter's cg base
        const int qn = ((qt + 1) & 3) * 2;           // next quarter's cg base

        int bx0[3], bx1[3];
        #pragma unroll
        for (int kx = 0; kx < 3; ++kx) {
            const int colb = (wn2 * 66 + l15 + kx) * 64;
            const int k7   = (l15 + kx) & 7;
            bx0[kx] = colb + ((0 + lg) ^ k7) * 8;
            bx1[kx] = colb + ((4 + lg) ^ k7) * 8;
        }

        TAPB(0,0,bx0,qb,qn) TAPB(0,1,bx0,qb,qn) TAPB(0,2,bx0,qb,qn)
        TAPB(0,3,bx0,qb,qn) TAPB(0,4,bx0,qb,qn) TAPB(0,5,bx0,qb,qn)
        TAPB(0,6,bx0,qb,qn) TAPB(0,7,bx0,qb,qn) TAPB(0,8,bx0,qb,qn)
        TAPB(1,0,bx1,qb,qn) TAPB(1,1,bx1,qb,qn) TAPB(1,2,bx1,qb,qn)
        TAPB(1,3,bx1,qb,qn) TAPB(1,4,bx1,qb,qn) TAPB(1,5,bx1,qb,qn)
        TAPB(1,6,bx1,qb,qn) TAPB(1,7,bx1,qb,qn) TAPB(1,8,bx1,qb,qn)
    }
    #undef TAPB
    #undef STAGE_X

    // drain outstanding dummy A loads before epilogue
    asm volatile("s_waitcnt vmcnt(0) lgkmcnt(0)" ::: "memory");
    __builtin_amdgcn_sched_barrier(0);

    // ---- epilogue: D col = co = l15, rows = sp -> f32x4 stores ----
    #pragma unroll
    for (int mi = 0; mi < 4; ++mi) {
        const int co = cohalf * 128 + wm * 64 + mi * 16 + l15;
        float* ob = out + ((size_t)(b * COUT + co)) * NSP
                  + ntile * 256 + wn * 128 + lg * 4;
        #pragma unroll
        for (int ni = 0; ni < 8; ++ni)
            *(f32x4*)(ob + (ni >> 2) * 64 + (ni & 3) * 16) = acc[mi][ni];
    }
}

// ---------------------------------------------------------------------------
// Fallback fp32 direct conv if workspace is too small.
// ---------------------------------------------------------------------------
__global__ __launch_bounds__(256)
void modconv_kernel(const float* __restrict__ x,
                    const float* __restrict__ cw,
                    const float* __restrict__ s,
                    const float* __restrict__ scale_p,
                    float* __restrict__ out) {
    const int tile = blockIdx.x;
    const int co   = blockIdx.y;
    const int b    = blockIdx.z;
    const int tid  = threadIdx.x;
    const float scale = scale_p[0];

    __shared__ float s_wt[CIN * KW];
    __shared__ float s_x[18 * 66];
    __shared__ float red[4];

    const float* cwb = cw + (size_t)co * CIN * KW;
    const float* sb  = s + b * CIN;
    float sumsq = 0.f;
    for (int i = tid; i < CIN * KW; i += 256) {
        float v = cwb[i] * scale * sb[i / KW];
        s_wt[i] = v;
        sumsq += v * v;
    }
    #pragma unroll
    for (int off = 32; off > 0; off >>= 1) sumsq += __shfl_down(sumsq, off);
    if ((tid & 63) == 0) red[tid >> 6] = sumsq;
    __syncthreads();
    const float demod = rsqrtf(red[0] + red[1] + red[2] + red[3] + 1e-8f);
    for (int i = tid; i < CIN * KW; i += 256) s_wt[i] *= demod;

    const int tx = tid & 63;
    const int tr = tid >> 6;
    const int y0 = tile * 16;
    float acc[4] = {0.f, 0.f, 0.f, 0.f};

    for (int ci = 0; ci < CIN; ++ci) {
        __syncthreads();
        const float* xb = x + ((size_t)(b * CIN + ci)) * (HH * WWS);
        for (int idx = tid; idx < 18 * 66; idx += 256) {
            const int r = idx / 66, c = idx % 66;
            const int yg = y0 - 1 + r, xg = c - 1;
            float v = 0.f;
            if (yg >= 0 && yg < HH && xg >= 0 && xg < WWS) v = xb[yg * WWS + xg];
            s_x[idx] = v;
        }
        __syncthreads();
        const float* wr = s_wt + ci * KW;
        const float w0 = wr[0], w1 = wr[1], w2 = wr[2];
        const float w3 = wr[3], w4 = wr[4], w5 = wr[5];
        const float w6 = wr[6], w7 = wr[7], w8 = wr[8];
        const int rbase = tr * 4;
        float xv[6][3];
        #pragma unroll
        for (int j = 0; j < 6; ++j)
            #pragma unroll
            for (int k = 0; k < 3; ++k) xv[j][k] = s_x[(rbase + j) * 66 + tx + k];
        #pragma unroll
        for (int i = 0; i < 4; ++i)
            acc[i] += w0 * xv[i][0] + w1 * xv[i][1] + w2 * xv[i][2]
                    + w3 * xv[i+1][0] + w4 * xv[i+1][1] + w5 * xv[i+1][2]
                    + w6 * xv[i+2][0] + w7 * xv[i+2][1] + w8 * xv[i+2][2];
    }
    float* ob = out + (((size_t)(b * COUT + co)) * HH + y0) * WWS + tx;
    #pragma unroll
    for (int i = 0; i < 4; ++i) ob[(tr * 4 + i) * WWS] = acc[i];
}

// ---------------------------------------------------------------------------
extern "C" void kernel_launch(void* const* d_in, const int* in_sizes, int n_in,
                              void* d_out, int out_size, void* d_ws, size_t ws_size,
                              hipStream_t stream) {
    const float* x       = (const float*)d_in[0];
    const float* w       = (const float*)d_in[1];
    const float* cw      = (const float*)d_in[2];
    const float* style_w = (const float*)d_in[3];
    const float* style_b = (const float*)d_in[4];
    const float* scale_p = (const float*)d_in[5];
    float*       out     = (float*)d_out;

    float*    s    = (float*)d_ws;
    ushort_t* wswt = (ushort_t*)((char*)d_ws + WT_OFF);
    ushort_t* wsx  = (ushort_t*)((char*)d_ws + X_OFF);
    float*    zp   = (float*)((char*)d_ws + ZP_OFF);

    style_kernel<<<dim3(BB), 256, 0, stream>>>(w, style_w, style_b, s);

    if (ws_size >= WS_NEEDED) {
        wt_kernel<<<dim3(COUT, BB), 256, 0, stream>>>(cw, s, scale_p, wswt, zp);
        xpose_kernel<<<dim3(64, 4, BB), 256, 0, stream>>>(x, wsx);
        conv_mfma_kernel<<<dim3(512), 256, 0, stream>>>(wswt, wsx,
                                                        (const ushort_t*)zp, out);
    } else {
        modconv_kernel<<<dim3(4, COUT, BB), 256, 0, stream>>>(x, cw, s, scale_p, out);
    }
}